// Round 13
// baseline (191.627 us; speedup 1.0000x reference)
//

#include <hip/hip_runtime.h>
#include <hip/hip_bf16.h>

// Deterministic hard_voxelize. Round 28: R27 skeleton (157.9us, proven) +
// serial-stage overlap. The suffix lookup (~18us, largest ours) depends only
// on tab/tag (ready after insert), not on scan1/scan2p — hits need prefix
// ranks only at RESOLVE time (~7K of 1.8M pts). So suffix probes now run in
// the scan1 dispatch (blocks beyond scan1's 720), emitting verified-hit
// point indices into a 64-way-sharded hit buffer (sharded: single-hot-line
// returning atomics serialize ~7ns each, R12). The assign dispatch gains a
// mostly-empty resolve range (re-probe quiescent tab -> f -> v -> append).
// k_write's insertion-sort of list indices makes append order irrelevant.
// Host-side: if the hit buffer doesn't fit ws, fall back to R27 arrangement
// (suffix probes inside assign) — max-N robustness unchanged.
// Pipeline: init, insert, {scan1 || suffix-probe}, scan2p,
// {assign+resolve|(+gated finit)}, [4 gated fallback], write = 10 dispatches.
// Measured laws: scattered 64B RMW ~1.45TB/s; hot-line returning atomics
// ~7ns (R12); returning-atomic+scatter ~0.5TB/s (R17); single-CU serial
// scans transaction-bound (R16); suffix latency-profile, MLP x4 optimal w/
// TLP saturated (R19/R24/R25); dispatch gap ~1-2us (R23); poison fill ~43us
// not ours; NO cooperative launch (R21).

#define MAXV 150000
#define MAXP 10
#define LCAP 12
#define GXC 1504
#define GYC 1504
#define GZC 40

#define PPREF 184320           // prefix length (720 blocks); distinct >> MAXV
#define HC 19
#define HCAP (1u << HC)        // 524288 slots; load ~0.35 at P=184K
#define HMASK (HCAP - 1u)
#define NSHARD 64

#define OUT_COORS 7500000
#define OUT_NPV   7950000
#define OUT_VNUM  8100000
#define EMPTY64 0xFFFFFFFFFFFFFFFFULL

typedef unsigned char u8;
typedef unsigned short u16;
typedef unsigned int u32;
typedef unsigned long long u64;

// 16B vector load legal at 4B alignment on gfx950 (dword ops need 4B align).
typedef struct __attribute__((packed, aligned(4))) { float x, y, z, w; } f4u;

__device__ __forceinline__ u16 f2bf(float v) {  // round-to-nearest-even
    u32 b = __float_as_uint(v);
    return (u16)((b + 0x7FFFu + ((b >> 16) & 1u)) >> 16);
}
__device__ __forceinline__ float bf2f(u16 u) {
    return __uint_as_float(((u32)u) << 16);
}
__device__ __forceinline__ float bfround(float v) { return bf2f(f2bf(v)); }

__device__ __forceinline__ u32 hslot(int key) {
    return (((u32)key * 2654435761u) >> 12) & HMASK;
}
__device__ __forceinline__ u16 htag(int key) {  // independent 2nd hash, !=0
    return (u16)((((u32)key) * 0x85EBCA6Bu) >> 16) | (u16)1;
}
__device__ __forceinline__ u32 fhslot(int key, u32 fhmask) {
    return (((u32)key * 2654435761u) >> 9) & fhmask;
}

__device__ __forceinline__ float load_ch(const void* pts, int i, int j, int bf) {
    if (bf) return bf2f(((const u16*)pts)[i * 5 + j]);
    return ((const float*)pts)[i * 5 + j];
}

// Exact f32 sub+div+floor, matching reference arithmetic. -1 if out of range.
// f32 path: one dwordx4 covers x,y,z (row stride 20B >= 16B, no OOB).
__device__ __forceinline__ int point_key(const void* pts, int i, int bf) {
    float x, y, z;
    if (bf) {
        const u16* p = (const u16*)pts + (size_t)i * 5;
        x = bf2f(p[0]); y = bf2f(p[1]); z = bf2f(p[2]);
    } else {
        f4u v = *(const f4u*)((const float*)pts + (size_t)i * 5);
        x = v.x; y = v.y; z = v.z;
    }
    int cx = (int)floorf((x - (-75.2f)) / 0.1f);
    int cy = (int)floorf((y - (-75.2f)) / 0.1f);
    int cz = (int)floorf((z - (-2.0f)) / 0.15f);
    if (cx < 0 || cx >= GXC || cy < 0 || cy >= GYC || cz < 0 || cz >= GZC) return -1;
    return (cz * GYC + cy) * GXC + cx;
}

// Init (+ fused dtype detect in block 0): tab=EMPTY, tag=0, cnt=0, hitcnt=0.
__global__ void k_init(u64* tab, u16* tag, int* cnt, u32* hitcnt, int N,
                       const u16* raw, int* dflag, int* total, int* fastflag) {
    if (blockIdx.x == 0) {
        __shared__ int v32;
        __shared__ int v16;
        if (threadIdx.x == 0) { v32 = 0; v16 = 0; }
        __syncthreads();
        int r = (int)threadIdx.x * 37;
        if (r >= N) r = N > 0 ? N - 1 : 0;
        const float* p32 = (const float*)raw;
        float a3 = p32[r * 5 + 3];
        float a4 = p32[r * 5 + 4];
        float b3 = bf2f(raw[r * 5 + 3]);
        float b4 = bf2f(raw[r * 5 + 4]);
        int ok32 = (a3 == a3) && (a4 == a4) &&
                   (a3 >= -0.001f) && (a3 <= 1.001f) && (a4 >= -0.001f) && (a4 <= 1.001f);
        int okbf = (b3 == b3) && (b4 == b4) &&
                   (b3 >= -0.001f) && (b3 <= 1.001f) && (b4 >= -0.001f) && (b4 <= 1.001f);
        if (ok32) atomicAdd(&v32, 1);
        if (okbf) atomicAdd(&v16, 1);
        __syncthreads();
        if (threadIdx.x == 0) *dflag = (v16 > v32) ? 1 : 0;
    }
    int stride = gridDim.x * blockDim.x;
    int i0 = blockIdx.x * blockDim.x + threadIdx.x;
    for (u32 i = (u32)i0; i < HCAP; i += (u32)stride) {
        tab[i] = EMPTY64;
        tag[i] = 0;
    }
    for (int i = i0; i < MAXV; i += stride) cnt[i] = 0;
    for (int i = i0; i < NSHARD; i += stride) hitcnt[i] = 0u;
    if (i0 == 0) { *total = 0; *fastflag = 0; }
}

// Canonical kernel: PURE packed u64 hash insert over the prefix.
// CAS-claim (winner writes tag); same-key -> atomicMin by point idx.
__global__ void Voxelization_87136296501765_kernel(
        const void* pts, int Peff, const int* dflag, u64* tab, u16* tag) {
    int i = blockIdx.x * 256 + threadIdx.x;
    if (i >= Peff) return;
    int key = point_key(pts, i, *dflag);
    if (key < 0) return;
    u64 mine = ((u64)(u32)key << 32) | (u32)i;
    u32 slot = hslot(key);
    for (;;) {                      // claims <= Peff <= HCAP/2: terminates
        u64 prev = atomicCAS(&tab[slot], EMPTY64, mine);
        if (prev == EMPTY64) { tag[slot] = htag(key); break; }
        if ((u32)(prev >> 32) == (u32)key) {
            if ((u32)prev > (u32)i) atomicMin(&tab[slot], mine);
            break;
        }
        slot = (slot + 1u) & HMASK;
    }
}

// Fused: blocks [0,nbp) = prefix rank scan (is-first by probing the
// quiescent table); blocks [nbp, nbp+nbs4s) = suffix probes (MLP x4,
// tag-filtered), verified hits -> sharded hit buffer (resolved after
// scan2p). Suffix portion depends only on tab/tag -> overlaps scan1.
__global__ void k_scan1(const void* pts, int N, int Peff, const int* dflag,
                        const u64* tab, const u16* tag,
                        u8* flags, u8* prefix, int* bsums,
                        int nbp, int nbs4s,
                        u32* hitcnt, int* hitbuf, int scap_shift) {
    __shared__ int sh[256];
    int b = blockIdx.x;
    int t = threadIdx.x;
    if (b >= nbp) {                 // ---- suffix probe portion ----
        int bf = *dflag;
        int base = Peff + (b - nbp) * 1024 + t;
        int shard = (b - nbp) & (NSHARD - 1);
        int idx[4];
        int key[4];
#pragma unroll
        for (int s = 0; s < 4; s++) {        // 4 independent pts chains
            int i = base + s * 256;
            idx[s] = i;
            key[s] = (i < N) ? point_key(pts, i, bf) : -1;
        }
        u32 slot[4];
        u16 tg[4];
        u16 g[4];
#pragma unroll
        for (int s = 0; s < 4; s++) {        // 4 independent tag loads
            if (key[s] >= 0) {
                slot[s] = hslot(key[s]);
                tg[s] = htag(key[s]);
                g[s] = tag[slot[s]];
            }
        }
#pragma unroll
        for (int s = 0; s < 4; s++) {        // resolve (tag-hit ~0.65%)
            if (key[s] < 0) continue;
            u32 sl = slot[s];
            u16 gg = g[s];
            for (;;) {
                if (gg == 0) break;          // voxel not opened -> dropped
                if (gg == tg[s]) {
                    u64 e = tab[sl];
                    if ((u32)(e >> 32) == (u32)key[s]) {
                        u32 pos = atomicAdd(&hitcnt[shard], 1u);
                        hitbuf[((size_t)shard << scap_shift) + pos] = idx[s];
                        break;
                    }                        // false positive -> continue
                }
                sl = (sl + 1u) & HMASK;
                gg = tag[sl];
            }
        }
        return;
    }
    // ---- scan1 portion ----
    int i = b * 256 + t;
    int isf = 0;
    if (i < Peff) {
        int key = point_key(pts, i, *dflag);
        if (key >= 0) {
            u32 slot = hslot(key);
            for (;;) {
                u64 e = tab[slot];
                if ((u32)(e >> 32) == (u32)key) { isf = ((u32)e == (u32)i); break; }
                if (e == EMPTY64) break;   // unreachable (key inserted)
                slot = (slot + 1u) & HMASK;
            }
        }
        flags[i] = (u8)isf;
    }
    sh[t] = isf;
    __syncthreads();
    for (int off = 1; off < 256; off <<= 1) {
        int xv = (t >= off) ? sh[t - off] : 0;
        __syncthreads();
        sh[t] += xv;
        __syncthreads();
    }
    if (i < Peff) prefix[i] = (u8)(sh[t] - isf);
    if (t == 255) bsums[b] = sh[255];
}

// Single-block scan of nbp (<=720) chunk sums. Writes total, fastflag, vnum.
__global__ void k_scan2p(const int* bsums, int nbp, int* bpre,
                         int* total, int* fastflag, float* out) {
    __shared__ int sh[256];
    int t = threadIdx.x;
    int C = (nbp + 255) / 256;
    int lo = t * C;
    int hi = lo + C < nbp ? lo + C : nbp;
    int s = 0;
    for (int i = lo; i < hi; i++) s += bsums[i];
    sh[t] = s;
    __syncthreads();
    for (int off = 1; off < 256; off <<= 1) {
        int xv = (t >= off) ? sh[t - off] : 0;
        __syncthreads();
        sh[t] += xv;
        __syncthreads();
    }
    int run = sh[t] - s;
    for (int i = lo; i < hi; i++) { bpre[i] = run; run += bsums[i]; }
    if (t == 255) {
        int T = sh[255];
        *total = T;
        *fastflag = (T >= MAXV) ? 1 : 0;
        if (T > MAXV) T = MAXV;
        out[OUT_VNUM] = bfround((float)T);
    }
}

// Assign + hit-resolve (fused mode) / suffix lookup (plain mode) + gated
// fallback-init. Block ranges: [0,nbp) prefix assign; [nbp,nbp+nbs4a) plain
// suffix probes (0 in fused mode); [nbp+nbs4a, +nrb) hit resolve (0 in
// plain mode). !fast && hasSuffix: whole grid does gated fallback init.
__global__ void k_assign_lookup(const void* pts, int N, int Peff,
                                const int* dflag, const int* fastflag,
                                u8* flags, const u8* prefix,
                                const int* bpre, const u64* tab,
                                const u16* tag, int nbp, int nbs4a, int nrb,
                                int hasSuffix,
                                const u32* hitcnt, const int* hitbuf,
                                int scap_shift,
                                u64* firsts, int* cnt, int* lists,
                                u64* ftab, u32 fhcap) {
    int b = blockIdx.x;
    int t = threadIdx.x;
    int fast = *fastflag;
    if (fast || !hasSuffix) {
        if (b < nbp) {
            int i = b * 256 + t;
            if (i < Peff) {
                int key = point_key(pts, i, *dflag);
                if (key >= 0) {
                    if (flags[i]) {
                        int v = (int)prefix[i] + bpre[b];
                        if (v < MAXV)
                            firsts[v] = ((u64)(u32)key << 32) | (u32)i;
                    } else {
                        u32 slot = hslot(key);        // dup: find first idx
                        for (;;) {
                            u64 e = tab[slot];
                            if ((u32)(e >> 32) == (u32)key) {
                                u32 f = (u32)e;
                                int v = (int)prefix[f] + bpre[f >> 8];
                                if (v < MAXV) {
                                    int pos = atomicAdd(&cnt[v], 1);
                                    if (pos < LCAP) lists[v * LCAP + pos] = i;
                                }
                                break;
                            }
                            if (e == EMPTY64) break;  // unreachable
                            slot = (slot + 1u) & HMASK;
                        }
                    }
                }
            }
        } else if (b < nbp + nbs4a && fast) {
            // plain-mode suffix probes (R27 path; used when hitbuf can't fit)
            int bf = *dflag;
            int base = Peff + (b - nbp) * 1024 + t;
            int idx[4];
            int key[4];
#pragma unroll
            for (int s = 0; s < 4; s++) {
                int i = base + s * 256;
                idx[s] = i;
                key[s] = (i < N) ? point_key(pts, i, bf) : -1;
            }
            u32 slot[4];
            u16 tg[4];
            u16 g[4];
#pragma unroll
            for (int s = 0; s < 4; s++) {
                if (key[s] >= 0) {
                    slot[s] = hslot(key[s]);
                    tg[s] = htag(key[s]);
                    g[s] = tag[slot[s]];
                }
            }
#pragma unroll
            for (int s = 0; s < 4; s++) {
                if (key[s] < 0) continue;
                u32 sl = slot[s];
                u16 gg = g[s];
                for (;;) {
                    if (gg == 0) break;
                    if (gg == tg[s]) {
                        u64 e = tab[sl];
                        if ((u32)(e >> 32) == (u32)key[s]) {
                            u32 f = (u32)e;
                            int v = (int)prefix[f] + bpre[f >> 8];
                            if (v < MAXV) {
                                int pos = atomicAdd(&cnt[v], 1);
                                if (pos < LCAP) lists[v * LCAP + pos] = idx[s];
                            }
                            break;
                        }
                    }
                    sl = (sl + 1u) & HMASK;
                    gg = tag[sl];
                }
            }
        } else if (b < nbp + nbs4a + nrb && fast) {
            // fused-mode hit resolve (~7K records; most threads exit fast)
            int scap = 1 << scap_shift;
            int r = (b - nbp - nbs4a) * 256 + t;
            int shard = r >> scap_shift;
            int j = r & (scap - 1);
            if (shard < NSHARD && (u32)j < hitcnt[shard]) {
                int i = hitbuf[((size_t)shard << scap_shift) + j];
                int key = point_key(pts, i, *dflag);
                u32 slot = hslot(key);
                for (;;) {                    // guaranteed present
                    u64 e = tab[slot];
                    if ((u32)(e >> 32) == (u32)key) {
                        u32 f = (u32)e;
                        int v = (int)prefix[f] + bpre[f >> 8];
                        if (v < MAXV) {
                            int pos = atomicAdd(&cnt[v], 1);
                            if (pos < LCAP) lists[v * LCAP + pos] = i;
                        }
                        break;
                    }
                    slot = (slot + 1u) & HMASK;
                }
            }
        }
    } else {
        // gated fallback init (distinct(prefix) < MAXV, suffix exists)
        int tid = b * 256 + t;
        int gsz = gridDim.x * 256;
        for (u32 i = (u32)tid; i < fhcap; i += (u32)gsz) ftab[i] = EMPTY64;
        for (int i = tid; i < MAXV; i += gsz) cnt[i] = 0;
        int bf = *dflag;
        for (int i = tid; i < N; i += gsz)
            flags[i] = (u8)(point_key(pts, i, bf) >= 0);
    }
}

// ---- Gated fallback (distinct(prefix) < MAXV; never on bench input) ----

__global__ void k_finsert(const int* fastflag, int hasSuffix, const void* pts,
                          int N, const int* dflag, u64* ftab, u32 fhmask,
                          u8* flags) {
    if (*fastflag || !hasSuffix) return;
    int stride = gridDim.x * blockDim.x;
    int bf = *dflag;
    for (int i = blockIdx.x * blockDim.x + threadIdx.x; i < N; i += stride) {
        int key = point_key(pts, i, bf);
        if (key < 0) continue;
        u64 mine = ((u64)(u32)key << 32) | (u32)i;
        u32 slot = fhslot(key, fhmask);
        for (u32 tries = 0; tries <= fhmask; ++tries) {  // bounded
            u64 prev = atomicCAS(&ftab[slot], EMPTY64, mine);
            if (prev == EMPTY64) break;
            if ((u32)(prev >> 32) == (u32)key) {
                u32 pm = (u32)prev;
                u32 eidx;
                if (pm > (u32)i) {
                    u64 old = atomicMin(&ftab[slot], mine);
                    u32 om = (u32)old;
                    eidx = (om > (u32)i) ? om : (u32)i;
                } else {
                    eidx = (u32)i;
                }
                flags[eidx] = 0;   // flags written in prior dispatch: safe
                break;
            }
            slot = (slot + 1u) & fhmask;
        }
    }
}

__global__ void k_fscan1(const int* fastflag, int hasSuffix, const u8* flags,
                         u8* prefix, int* bsums, int n) {
    if (*fastflag || !hasSuffix) return;
    __shared__ int sh[256];
    int t = threadIdx.x;
    int nb = (n + 255) >> 8;
    for (int chunk = blockIdx.x; chunk < nb; chunk += gridDim.x) {
        int i = chunk * 256 + t;
        int v = (i < n) ? (int)flags[i] : 0;
        sh[t] = v;
        __syncthreads();
        for (int off = 1; off < 256; off <<= 1) {
            int xv = (t >= off) ? sh[t - off] : 0;
            __syncthreads();
            sh[t] += xv;
            __syncthreads();
        }
        if (i < n) prefix[i] = (u8)(sh[t] - v);
        if (t == 255) bsums[chunk] = sh[255];
        __syncthreads();
    }
}

__global__ void k_fscan2(const int* fastflag, int hasSuffix, const int* bsums,
                         int nb, int* bpre, int* total, float* out) {
    if (*fastflag || !hasSuffix) return;
    __shared__ int sh[256];
    int t = threadIdx.x;
    int C = (nb + 255) / 256;
    int lo = t * C;
    int hi = lo + C < nb ? lo + C : nb;
    int s = 0;
    for (int i = lo; i < hi; i++) s += bsums[i];
    sh[t] = s;
    __syncthreads();
    for (int off = 1; off < 256; off <<= 1) {
        int xv = (t >= off) ? sh[t - off] : 0;
        __syncthreads();
        sh[t] += xv;
        __syncthreads();
    }
    int run = sh[t] - s;
    for (int i = lo; i < hi; i++) { bpre[i] = run; run += bsums[i]; }
    if (t == 255) {
        int T = sh[255];
        *total = T;
        if (T > MAXV) T = MAXV;
        out[OUT_VNUM] = bfround((float)T);
    }
}

__global__ void k_fassign(const int* fastflag, int hasSuffix, const void* pts,
                          int N, const int* dflag, const u8* flags,
                          const u8* prefix, const int* bpre, const u64* ftab,
                          u32 fhmask, u64* firsts, int* cnt, int* lists) {
    if (*fastflag || !hasSuffix) return;
    int stride = gridDim.x * blockDim.x;
    int bf = *dflag;
    for (int i = blockIdx.x * blockDim.x + threadIdx.x; i < N; i += stride) {
        int key = point_key(pts, i, bf);
        if (key < 0) continue;
        if (flags[i]) {
            int v = (int)prefix[i] + bpre[i >> 8];
            if (v < MAXV)
                firsts[v] = ((u64)(u32)key << 32) | (u32)i;
        } else {
            u32 slot = fhslot(key, fhmask);
            for (u32 tries = 0; tries <= fhmask; ++tries) {
                u64 e = ftab[slot];
                if (e == EMPTY64) break;
                if ((u32)(e >> 32) == (u32)key) {
                    u32 f = (u32)e;
                    int v = (int)prefix[f] + bpre[f >> 8];
                    if (v < MAXV) {
                        int pos = atomicAdd(&cnt[v], 1);
                        if (pos < LCAP) lists[v * LCAP + pos] = i;
                    }
                    break;
                }
                slot = (slot + 1u) & fhmask;
            }
        }
    }
}

// Data row copy: f32 path reads ch0..3 via one dwordx4 + ch4 scalar.
__device__ __forceinline__ void write_row(const void* pts, int p, int bf,
                                          float* dst) {
    if (bf) {
        const u16* q = (const u16*)pts + (size_t)p * 5;
#pragma unroll
        for (int j = 0; j < 5; j++) dst[j] = bfround(bf2f(q[j]));
    } else {
        const float* base = (const float*)pts + (size_t)p * 5;
        f4u v = *(const f4u*)base;
        dst[0] = bfround(v.x);
        dst[1] = bfround(v.y);
        dst[2] = bfround(v.z);
        dst[3] = bfround(v.w);
        dst[4] = bfround(base[4]);
    }
}

// Sole output writer (d_out is poisoned each call): per v zero-fills the
// 200B row via 25 float2 stores, then overwrites the ~1.05 data rows;
// coors (coalesced in v), npv.
__global__ void k_write(const void* pts, const int* dflag, const u64* firsts,
                        const int* cnt, const int* lists, const int* total,
                        float* out) {
    int v = blockIdx.x * blockDim.x + threadIdx.x;
    if (v >= MAXV) return;
    int T = *total;
    if (T > MAXV) T = MAXV;
    float* dst = out + (size_t)v * MAXP * 5;
    float2* d2 = (float2*)dst;          // v*200B -> 8B aligned
#pragma unroll
    for (int j = 0; j < 25; j++) d2[j] = make_float2(0.0f, 0.0f);
    if (v >= T) {
        out[OUT_COORS + v * 3 + 0] = -1.0f;
        out[OUT_COORS + v * 3 + 1] = -1.0f;
        out[OUT_COORS + v * 3 + 2] = -1.0f;
        out[OUT_NPV + v] = 0.0f;
        return;
    }
    u64 fe = firsts[v];
    u32 key = (u32)(fe >> 32);
    int f = (int)(u32)fe;
    int cx = (int)(key % GXC);
    u32 r = key / GXC;
    int cy = (int)(r % GYC);
    int cz = (int)(r / GYC);
    out[OUT_COORS + v * 3 + 0] = bfround((float)cz);
    out[OUT_COORS + v * 3 + 1] = bfround((float)cy);
    out[OUT_COORS + v * 3 + 2] = bfround((float)cx);
    int c = cnt[v];
    int np = 1 + c;
    if (np > MAXP) np = MAXP;
    out[OUT_NPV + v] = (float)np;
    int bf = *dflag;
    write_row(pts, f, bf, dst);
    if (c > 0) {
        int m = (c < LCAP) ? c : LCAP;
        int idx[LCAP];
        for (int j = 0; j < m; j++) idx[j] = lists[v * LCAP + j];
        for (int a = 1; a < m; a++) {  // sort dup indices -> insertion order
            int kk = idx[a];
            int b2 = a - 1;
            while (b2 >= 0 && idx[b2] > kk) { idx[b2 + 1] = idx[b2]; b2--; }
            idx[b2 + 1] = kk;
        }
        for (int rr = 1; rr < np; rr++)
            write_row(pts, idx[rr - 1], bf, dst + rr * 5);
    }
}

extern "C" void kernel_launch(void* const* d_in, const int* in_sizes, int n_in,
                              void* d_out, int out_size, void* d_ws, size_t ws_size,
                              hipStream_t stream) {
    (void)n_in; (void)out_size;
    const void* pts = d_in[0];
    int N = in_sizes[0] / 5;
    float* out = (float*)d_out;
    if (N <= 0 || N > 16384 * 256) return;

    int Peff = N < PPREF ? N : PPREF;
    int nbp = (Peff + 255) / 256;
    int nbs4 = (N > Peff) ? (N - Peff + 1023) / 1024 : 0;
    int nb = (N + 255) / 256;
    int hasSuffix = (N > Peff) ? 1 : 0;
    size_t npad = ((size_t)N + 255) & ~(size_t)255;

    // Sharded hit buffer geometry (fused mode): shard = suffix-block & 63;
    // per-shard worst case = ceil(nbs4/64)*1024 records; scap = next pow2.
    int bps = (nbs4 + NSHARD - 1) / NSHARD;
    int scap_shift = 10;
    while ((1 << scap_shift) < bps * 1024) scap_shift++;
    size_t hitsz = (size_t)NSHARD * ((size_t)4 << scap_shift);
    int nrb = (NSHARD << scap_shift) / 256;

    // ws: flags[npad] | prefix[npad] | bsums/bpre[16384]*4 | scalars |
    //     hitcnt[64]*4 | tab[HCAP]*8 | tag[HCAP]*2 | firsts[MAXV]*8 |
    //     cnt[MAXV]*4 | lists[MAXV*LCAP]*4 | [hitbuf, fused only] |
    //     ftab[fhcap]*8     (~43.6 MB fused at N=2M, fhcap=2^21)
    size_t base_need = npad + npad + 16384 * 8 + 512 + 256
                + (size_t)HCAP * 8 + (size_t)HCAP * 2
                + (size_t)MAXV * 8 + (size_t)MAXV * 4 + (size_t)MAXV * LCAP * 4;
    if (ws_size < base_need + ((size_t)8 << 21)) return;
    int fused = (hasSuffix &&
                 ws_size >= base_need + hitsz + ((size_t)8 << 21)) ? 1 : 0;
    size_t used = base_need + (fused ? hitsz : 0);
    u32 fhcap = (ws_size >= used + ((size_t)8 << 22)) ? (1u << 22) : (1u << 21);
    u32 fhmask = fhcap - 1u;

    char* w = (char*)d_ws;
    u8*  flags  = (u8*)w;   w += npad;
    u8*  prefix = (u8*)w;   w += npad;
    int* bsums  = (int*)w;  w += 16384 * 4;
    int* bpre   = (int*)w;  w += 16384 * 4;
    int* total  = (int*)w;  w += 128;
    int* dflag  = (int*)w;  w += 128;
    int* fastflag = (int*)w; w += 256;
    u32* hitcnt = (u32*)w;  w += 256;
    u64* tab    = (u64*)w;  w += (size_t)HCAP * 8;
    u16* tag    = (u16*)w;  w += (size_t)HCAP * 2;
    u64* firsts = (u64*)w;  w += (size_t)MAXV * 8;
    int* cnt    = (int*)w;  w += (size_t)MAXV * 4;
    int* lists  = (int*)w;  w += (size_t)MAXV * LCAP * 4;
    int* hitbuf = (int*)w;  w += fused ? hitsz : 0;
    u64* ftab   = (u64*)w;

    int nbs4s = fused ? nbs4 : 0;       // suffix blocks in scan1 dispatch
    int nbs4a = fused ? 0 : nbs4;       // suffix blocks in assign dispatch
    int nrb_a = fused ? nrb : 0;        // resolve blocks in assign dispatch

    k_init<<<2048, 256, 0, stream>>>(tab, tag, cnt, hitcnt, N,
                                     (const u16*)pts, dflag, total, fastflag);
    Voxelization_87136296501765_kernel<<<nbp, 256, 0, stream>>>(
        pts, Peff, dflag, tab, tag);
    k_scan1<<<nbp + nbs4s, 256, 0, stream>>>(
        pts, N, Peff, dflag, tab, tag, flags, prefix, bsums,
        nbp, nbs4s, hitcnt, hitbuf, scap_shift);
    k_scan2p<<<1, 256, 0, stream>>>(bsums, nbp, bpre, total, fastflag, out);
    k_assign_lookup<<<nbp + nbs4a + nrb_a, 256, 0, stream>>>(
        pts, N, Peff, dflag, fastflag, flags, prefix, bpre, tab, tag,
        nbp, nbs4a, nrb_a, hasSuffix, hitcnt, hitbuf, scap_shift,
        firsts, cnt, lists, ftab, fhcap);
    if (hasSuffix) {
        k_finsert<<<2048, 256, 0, stream>>>(fastflag, hasSuffix, pts, N,
                                            dflag, ftab, fhmask, flags);
        k_fscan1<<<2048, 256, 0, stream>>>(fastflag, hasSuffix, flags,
                                           prefix, bsums, N);
        k_fscan2<<<1, 256, 0, stream>>>(fastflag, hasSuffix, bsums, nb, bpre,
                                        total, out);
        k_fassign<<<2048, 256, 0, stream>>>(fastflag, hasSuffix, pts, N,
                                            dflag, flags, prefix, bpre, ftab,
                                            fhmask, firsts, cnt, lists);
    }
    k_write<<<(MAXV + 255) / 256, 256, 0, stream>>>(pts, dflag, firsts, cnt,
                                                    lists, total, out);
}

// Round 14
// 159.345 us; speedup vs baseline: 1.2026x; 1.2026x over previous
//

#include <hip/hip_runtime.h>
#include <hip/hip_bf16.h>

// Deterministic hard_voxelize. Round 29: exact revert to R27 (157.9us, best).
// R28 post-mortem: fusing suffix probes into the scan1 dispatch REGRESSED
// (54.9us fused vs ~25us sum-of-parts; total 191.6). Law added: a kernel
// with a per-block barrier ladder (the scan) is a bad co-residency partner
// for a latency-bound gather — barrier-parked waves hold CU slots without
// issuing, throttling the gather's latency hiding; plus hit-emission via
// returning atomics on 4 hot lines re-created the R12/R17 poison chain.
// Tested-and-rejected levers: coop launch (R21, breaks graph capture);
// dispatch-count cuts (R23, neutral); MLP x8 (R25, TLP-starved); NT loads
// (R25, breaks line reuse); scan||suffix overlap (R28). Remaining wall =
// harness poison fills (~43us each) + insert at scattered-RMW law + suffix
// at TLP-saturated latency floor (MLP x4) + write store floor + ~10 small
// dispatch gaps.
//  - PPREF 184320: distinct(184320) ~= 183.9K >> 150K (fallback covers
//    adversarial).
//  - Suffix lookup MLP x4, tag-filtered (1MB tag L2-resident; 4MB tab
//    touched only on ~0.65% tag match).
//  - f32 point_key via one dwordx4 (4B-aligned); k_write zero-fill via 25
//    float2 stores + vectorized data-row copy.
// Pipeline: init, insert, scan1, scan2p, assign+lookup(+gated finit),
// [4 gated fallback], write = 10 plain dispatches.

#define MAXV 150000
#define MAXP 10
#define LCAP 12
#define GXC 1504
#define GYC 1504
#define GZC 40

#define PPREF 184320           // prefix length (720 blocks); distinct >> MAXV
#define HC 19
#define HCAP (1u << HC)        // 524288 slots; load ~0.35 at P=184K
#define HMASK (HCAP - 1u)

#define OUT_COORS 7500000
#define OUT_NPV   7950000
#define OUT_VNUM  8100000
#define EMPTY64 0xFFFFFFFFFFFFFFFFULL

typedef unsigned char u8;
typedef unsigned short u16;
typedef unsigned int u32;
typedef unsigned long long u64;

// 16B vector load legal at 4B alignment on gfx950 (dword ops need 4B align).
typedef struct __attribute__((packed, aligned(4))) { float x, y, z, w; } f4u;

__device__ __forceinline__ u16 f2bf(float v) {  // round-to-nearest-even
    u32 b = __float_as_uint(v);
    return (u16)((b + 0x7FFFu + ((b >> 16) & 1u)) >> 16);
}
__device__ __forceinline__ float bf2f(u16 u) {
    return __uint_as_float(((u32)u) << 16);
}
__device__ __forceinline__ float bfround(float v) { return bf2f(f2bf(v)); }

__device__ __forceinline__ u32 hslot(int key) {
    return (((u32)key * 2654435761u) >> 12) & HMASK;
}
__device__ __forceinline__ u16 htag(int key) {  // independent 2nd hash, !=0
    return (u16)((((u32)key) * 0x85EBCA6Bu) >> 16) | (u16)1;
}
__device__ __forceinline__ u32 fhslot(int key, u32 fhmask) {
    return (((u32)key * 2654435761u) >> 9) & fhmask;
}

__device__ __forceinline__ float load_ch(const void* pts, int i, int j, int bf) {
    if (bf) return bf2f(((const u16*)pts)[i * 5 + j]);
    return ((const float*)pts)[i * 5 + j];
}

// Exact f32 sub+div+floor, matching reference arithmetic. -1 if out of range.
// f32 path: one dwordx4 covers x,y,z (row stride 20B >= 16B, no OOB).
__device__ __forceinline__ int point_key(const void* pts, int i, int bf) {
    float x, y, z;
    if (bf) {
        const u16* p = (const u16*)pts + (size_t)i * 5;
        x = bf2f(p[0]); y = bf2f(p[1]); z = bf2f(p[2]);
    } else {
        f4u v = *(const f4u*)((const float*)pts + (size_t)i * 5);
        x = v.x; y = v.y; z = v.z;
    }
    int cx = (int)floorf((x - (-75.2f)) / 0.1f);
    int cy = (int)floorf((y - (-75.2f)) / 0.1f);
    int cz = (int)floorf((z - (-2.0f)) / 0.15f);
    if (cx < 0 || cx >= GXC || cy < 0 || cy >= GYC || cz < 0 || cz >= GZC) return -1;
    return (cz * GYC + cy) * GXC + cx;
}

// Init (+ fused dtype detect in block 0): tab=EMPTY, tag=0, cnt=0, scalars.
__global__ void k_init(u64* tab, u16* tag, int* cnt, int N, const u16* raw,
                       int* dflag, int* total, int* fastflag) {
    if (blockIdx.x == 0) {
        __shared__ int v32;
        __shared__ int v16;
        if (threadIdx.x == 0) { v32 = 0; v16 = 0; }
        __syncthreads();
        int r = (int)threadIdx.x * 37;
        if (r >= N) r = N > 0 ? N - 1 : 0;
        const float* p32 = (const float*)raw;
        float a3 = p32[r * 5 + 3];
        float a4 = p32[r * 5 + 4];
        float b3 = bf2f(raw[r * 5 + 3]);
        float b4 = bf2f(raw[r * 5 + 4]);
        int ok32 = (a3 == a3) && (a4 == a4) &&
                   (a3 >= -0.001f) && (a3 <= 1.001f) && (a4 >= -0.001f) && (a4 <= 1.001f);
        int okbf = (b3 == b3) && (b4 == b4) &&
                   (b3 >= -0.001f) && (b3 <= 1.001f) && (b4 >= -0.001f) && (b4 <= 1.001f);
        if (ok32) atomicAdd(&v32, 1);
        if (okbf) atomicAdd(&v16, 1);
        __syncthreads();
        if (threadIdx.x == 0) *dflag = (v16 > v32) ? 1 : 0;
    }
    int stride = gridDim.x * blockDim.x;
    int i0 = blockIdx.x * blockDim.x + threadIdx.x;
    for (u32 i = (u32)i0; i < HCAP; i += (u32)stride) {
        tab[i] = EMPTY64;
        tag[i] = 0;
    }
    for (int i = i0; i < MAXV; i += stride) cnt[i] = 0;
    if (i0 == 0) { *total = 0; *fastflag = 0; }
}

// Canonical kernel: PURE packed u64 hash insert over the prefix.
// CAS-claim (winner writes tag); same-key -> atomicMin by point idx.
__global__ void Voxelization_87136296501765_kernel(
        const void* pts, int Peff, const int* dflag, u64* tab, u16* tag) {
    int i = blockIdx.x * 256 + threadIdx.x;
    if (i >= Peff) return;
    int key = point_key(pts, i, *dflag);
    if (key < 0) return;
    u64 mine = ((u64)(u32)key << 32) | (u32)i;
    u32 slot = hslot(key);
    for (;;) {                      // claims <= Peff <= HCAP/2: terminates
        u64 prev = atomicCAS(&tab[slot], EMPTY64, mine);
        if (prev == EMPTY64) { tag[slot] = htag(key); break; }
        if ((u32)(prev >> 32) == (u32)key) {
            if ((u32)prev > (u32)i) atomicMin(&tab[slot], mine);
            break;
        }
        slot = (slot + 1u) & HMASK;
    }
}

// Rank scan over the prefix. is-first recomputed by probing the quiescent
// table: isf = (min idx at key's slot == i).
__global__ void k_scan1(const void* pts, int Peff, const int* dflag,
                        const u64* tab, u8* flags, u8* prefix, int* bsums) {
    __shared__ int sh[256];
    int t = threadIdx.x;
    int i = blockIdx.x * 256 + t;
    int isf = 0;
    if (i < Peff) {
        int key = point_key(pts, i, *dflag);
        if (key >= 0) {
            u32 slot = hslot(key);
            for (;;) {
                u64 e = tab[slot];
                if ((u32)(e >> 32) == (u32)key) { isf = ((u32)e == (u32)i); break; }
                if (e == EMPTY64) break;   // unreachable (key inserted)
                slot = (slot + 1u) & HMASK;
            }
        }
        flags[i] = (u8)isf;
    }
    sh[t] = isf;
    __syncthreads();
    for (int off = 1; off < 256; off <<= 1) {
        int xv = (t >= off) ? sh[t - off] : 0;
        __syncthreads();
        sh[t] += xv;
        __syncthreads();
    }
    if (i < Peff) prefix[i] = (u8)(sh[t] - isf);
    if (t == 255) bsums[blockIdx.x] = sh[255];
}

// Single-block scan of nbp (<=720) chunk sums. Writes total, fastflag, vnum.
__global__ void k_scan2p(const int* bsums, int nbp, int* bpre,
                         int* total, int* fastflag, float* out) {
    __shared__ int sh[256];
    int t = threadIdx.x;
    int C = (nbp + 255) / 256;
    int lo = t * C;
    int hi = lo + C < nbp ? lo + C : nbp;
    int s = 0;
    for (int i = lo; i < hi; i++) s += bsums[i];
    sh[t] = s;
    __syncthreads();
    for (int off = 1; off < 256; off <<= 1) {
        int xv = (t >= off) ? sh[t - off] : 0;
        __syncthreads();
        sh[t] += xv;
        __syncthreads();
    }
    int run = sh[t] - s;
    for (int i = lo; i < hi; i++) { bpre[i] = run; run += bsums[i]; }
    if (t == 255) {
        int T = sh[255];
        *total = T;
        *fastflag = (T >= MAXV) ? 1 : 0;
        if (T > MAXV) T = MAXV;
        out[OUT_VNUM] = bfround((float)T);
    }
}

// Fused assign + suffix lookup (MLP x4) + gated fallback-init.
__global__ void k_assign_lookup(const void* pts, int N, int Peff,
                                const int* dflag, const int* fastflag,
                                u8* flags, const u8* prefix,
                                const int* bpre, const u64* tab,
                                const u16* tag, int nbp, int nbs4,
                                int hasSuffix,
                                u64* firsts, int* cnt, int* lists,
                                u64* ftab, u32 fhcap) {
    int b = blockIdx.x;
    int t = threadIdx.x;
    int fast = *fastflag;
    if (fast || !hasSuffix) {
        if (b < nbp) {
            int i = b * 256 + t;
            if (i < Peff) {
                int key = point_key(pts, i, *dflag);
                if (key >= 0) {
                    if (flags[i]) {
                        int v = (int)prefix[i] + bpre[b];
                        if (v < MAXV)
                            firsts[v] = ((u64)(u32)key << 32) | (u32)i;
                    } else {
                        u32 slot = hslot(key);        // dup: find first idx
                        for (;;) {
                            u64 e = tab[slot];
                            if ((u32)(e >> 32) == (u32)key) {
                                u32 f = (u32)e;
                                int v = (int)prefix[f] + bpre[f >> 8];
                                if (v < MAXV) {
                                    int pos = atomicAdd(&cnt[v], 1);
                                    if (pos < LCAP) lists[v * LCAP + pos] = i;
                                }
                                break;
                            }
                            if (e == EMPTY64) break;  // unreachable
                            slot = (slot + 1u) & HMASK;
                        }
                    }
                }
            }
        } else if (b < nbp + nbs4 && fast) {
            int bf = *dflag;
            int base = Peff + (b - nbp) * 1024 + t;
            int idx[4];
            int key[4];
#pragma unroll
            for (int s = 0; s < 4; s++) {        // 4 independent pts chains
                int i = base + s * 256;
                idx[s] = i;
                key[s] = (i < N) ? point_key(pts, i, bf) : -1;
            }
            u32 slot[4];
            u16 tg[4];
            u16 g[4];
#pragma unroll
            for (int s = 0; s < 4; s++) {        // 4 independent tag loads
                if (key[s] >= 0) {
                    slot[s] = hslot(key[s]);
                    tg[s] = htag(key[s]);
                    g[s] = tag[slot[s]];
                }
            }
#pragma unroll
            for (int s = 0; s < 4; s++) {        // resolve (tag-hit ~0.65%)
                if (key[s] < 0) continue;
                u32 sl = slot[s];
                u16 gg = g[s];
                for (;;) {
                    if (gg == 0) break;          // voxel not opened -> dropped
                    if (gg == tg[s]) {
                        u64 e = tab[sl];
                        if ((u32)(e >> 32) == (u32)key[s]) {
                            u32 f = (u32)e;
                            int v = (int)prefix[f] + bpre[f >> 8];
                            if (v < MAXV) {
                                int pos = atomicAdd(&cnt[v], 1);
                                if (pos < LCAP) lists[v * LCAP + pos] = idx[s];
                            }
                            break;
                        }                        // false positive -> continue
                    }
                    sl = (sl + 1u) & HMASK;
                    gg = tag[sl];
                }
            }
        }
    } else {
        // gated fallback init (distinct(prefix) < MAXV, suffix exists)
        int tid = b * 256 + t;
        int gsz = gridDim.x * 256;
        for (u32 i = (u32)tid; i < fhcap; i += (u32)gsz) ftab[i] = EMPTY64;
        for (int i = tid; i < MAXV; i += gsz) cnt[i] = 0;
        int bf = *dflag;
        for (int i = tid; i < N; i += gsz)
            flags[i] = (u8)(point_key(pts, i, bf) >= 0);
    }
}

// ---- Gated fallback (distinct(prefix) < MAXV; never on bench input) ----

__global__ void k_finsert(const int* fastflag, int hasSuffix, const void* pts,
                          int N, const int* dflag, u64* ftab, u32 fhmask,
                          u8* flags) {
    if (*fastflag || !hasSuffix) return;
    int stride = gridDim.x * blockDim.x;
    int bf = *dflag;
    for (int i = blockIdx.x * blockDim.x + threadIdx.x; i < N; i += stride) {
        int key = point_key(pts, i, bf);
        if (key < 0) continue;
        u64 mine = ((u64)(u32)key << 32) | (u32)i;
        u32 slot = fhslot(key, fhmask);
        for (u32 tries = 0; tries <= fhmask; ++tries) {  // bounded
            u64 prev = atomicCAS(&ftab[slot], EMPTY64, mine);
            if (prev == EMPTY64) break;
            if ((u32)(prev >> 32) == (u32)key) {
                u32 pm = (u32)prev;
                u32 eidx;
                if (pm > (u32)i) {
                    u64 old = atomicMin(&ftab[slot], mine);
                    u32 om = (u32)old;
                    eidx = (om > (u32)i) ? om : (u32)i;
                } else {
                    eidx = (u32)i;
                }
                flags[eidx] = 0;   // flags written in prior dispatch: safe
                break;
            }
            slot = (slot + 1u) & fhmask;
        }
    }
}

__global__ void k_fscan1(const int* fastflag, int hasSuffix, const u8* flags,
                         u8* prefix, int* bsums, int n) {
    if (*fastflag || !hasSuffix) return;
    __shared__ int sh[256];
    int t = threadIdx.x;
    int nb = (n + 255) >> 8;
    for (int chunk = blockIdx.x; chunk < nb; chunk += gridDim.x) {
        int i = chunk * 256 + t;
        int v = (i < n) ? (int)flags[i] : 0;
        sh[t] = v;
        __syncthreads();
        for (int off = 1; off < 256; off <<= 1) {
            int xv = (t >= off) ? sh[t - off] : 0;
            __syncthreads();
            sh[t] += xv;
            __syncthreads();
        }
        if (i < n) prefix[i] = (u8)(sh[t] - v);
        if (t == 255) bsums[chunk] = sh[255];
        __syncthreads();
    }
}

__global__ void k_fscan2(const int* fastflag, int hasSuffix, const int* bsums,
                         int nb, int* bpre, int* total, float* out) {
    if (*fastflag || !hasSuffix) return;
    __shared__ int sh[256];
    int t = threadIdx.x;
    int C = (nb + 255) / 256;
    int lo = t * C;
    int hi = lo + C < nb ? lo + C : nb;
    int s = 0;
    for (int i = lo; i < hi; i++) s += bsums[i];
    sh[t] = s;
    __syncthreads();
    for (int off = 1; off < 256; off <<= 1) {
        int xv = (t >= off) ? sh[t - off] : 0;
        __syncthreads();
        sh[t] += xv;
        __syncthreads();
    }
    int run = sh[t] - s;
    for (int i = lo; i < hi; i++) { bpre[i] = run; run += bsums[i]; }
    if (t == 255) {
        int T = sh[255];
        *total = T;
        if (T > MAXV) T = MAXV;
        out[OUT_VNUM] = bfround((float)T);
    }
}

__global__ void k_fassign(const int* fastflag, int hasSuffix, const void* pts,
                          int N, const int* dflag, const u8* flags,
                          const u8* prefix, const int* bpre, const u64* ftab,
                          u32 fhmask, u64* firsts, int* cnt, int* lists) {
    if (*fastflag || !hasSuffix) return;
    int stride = gridDim.x * blockDim.x;
    int bf = *dflag;
    for (int i = blockIdx.x * blockDim.x + threadIdx.x; i < N; i += stride) {
        int key = point_key(pts, i, bf);
        if (key < 0) continue;
        if (flags[i]) {
            int v = (int)prefix[i] + bpre[i >> 8];
            if (v < MAXV)
                firsts[v] = ((u64)(u32)key << 32) | (u32)i;
        } else {
            u32 slot = fhslot(key, fhmask);
            for (u32 tries = 0; tries <= fhmask; ++tries) {
                u64 e = ftab[slot];
                if (e == EMPTY64) break;
                if ((u32)(e >> 32) == (u32)key) {
                    u32 f = (u32)e;
                    int v = (int)prefix[f] + bpre[f >> 8];
                    if (v < MAXV) {
                        int pos = atomicAdd(&cnt[v], 1);
                        if (pos < LCAP) lists[v * LCAP + pos] = i;
                    }
                    break;
                }
                slot = (slot + 1u) & fhmask;
            }
        }
    }
}

// Data row copy: f32 path reads ch0..3 via one dwordx4 + ch4 scalar.
__device__ __forceinline__ void write_row(const void* pts, int p, int bf,
                                          float* dst) {
    if (bf) {
        const u16* q = (const u16*)pts + (size_t)p * 5;
#pragma unroll
        for (int j = 0; j < 5; j++) dst[j] = bfround(bf2f(q[j]));
    } else {
        const float* base = (const float*)pts + (size_t)p * 5;
        f4u v = *(const f4u*)base;
        dst[0] = bfround(v.x);
        dst[1] = bfround(v.y);
        dst[2] = bfround(v.z);
        dst[3] = bfround(v.w);
        dst[4] = bfround(base[4]);
    }
}

// Sole output writer (d_out is poisoned each call): per v zero-fills the
// 200B row via 25 float2 stores, then overwrites the ~1.05 data rows;
// coors (coalesced in v), npv.
__global__ void k_write(const void* pts, const int* dflag, const u64* firsts,
                        const int* cnt, const int* lists, const int* total,
                        float* out) {
    int v = blockIdx.x * blockDim.x + threadIdx.x;
    if (v >= MAXV) return;
    int T = *total;
    if (T > MAXV) T = MAXV;
    float* dst = out + (size_t)v * MAXP * 5;
    float2* d2 = (float2*)dst;          // v*200B -> 8B aligned
#pragma unroll
    for (int j = 0; j < 25; j++) d2[j] = make_float2(0.0f, 0.0f);
    if (v >= T) {
        out[OUT_COORS + v * 3 + 0] = -1.0f;
        out[OUT_COORS + v * 3 + 1] = -1.0f;
        out[OUT_COORS + v * 3 + 2] = -1.0f;
        out[OUT_NPV + v] = 0.0f;
        return;
    }
    u64 fe = firsts[v];
    u32 key = (u32)(fe >> 32);
    int f = (int)(u32)fe;
    int cx = (int)(key % GXC);
    u32 r = key / GXC;
    int cy = (int)(r % GYC);
    int cz = (int)(r / GYC);
    out[OUT_COORS + v * 3 + 0] = bfround((float)cz);
    out[OUT_COORS + v * 3 + 1] = bfround((float)cy);
    out[OUT_COORS + v * 3 + 2] = bfround((float)cx);
    int c = cnt[v];
    int np = 1 + c;
    if (np > MAXP) np = MAXP;
    out[OUT_NPV + v] = (float)np;
    int bf = *dflag;
    write_row(pts, f, bf, dst);
    if (c > 0) {
        int m = (c < LCAP) ? c : LCAP;
        int idx[LCAP];
        for (int j = 0; j < m; j++) idx[j] = lists[v * LCAP + j];
        for (int a = 1; a < m; a++) {  // sort dup indices -> insertion order
            int kk = idx[a];
            int b2 = a - 1;
            while (b2 >= 0 && idx[b2] > kk) { idx[b2 + 1] = idx[b2]; b2--; }
            idx[b2 + 1] = kk;
        }
        for (int rr = 1; rr < np; rr++)
            write_row(pts, idx[rr - 1], bf, dst + rr * 5);
    }
}

extern "C" void kernel_launch(void* const* d_in, const int* in_sizes, int n_in,
                              void* d_out, int out_size, void* d_ws, size_t ws_size,
                              hipStream_t stream) {
    (void)n_in; (void)out_size;
    const void* pts = d_in[0];
    int N = in_sizes[0] / 5;
    float* out = (float*)d_out;
    if (N <= 0 || N > 16384 * 256) return;

    int Peff = N < PPREF ? N : PPREF;
    int nbp = (Peff + 255) / 256;
    int nbs4 = (N > Peff) ? (N - Peff + 1023) / 1024 : 0;
    int nb = (N + 255) / 256;
    int hasSuffix = (N > Peff) ? 1 : 0;
    size_t npad = ((size_t)N + 255) & ~(size_t)255;

    // ws: flags[npad] | prefix[npad] | bsums/bpre[16384]*4 | scalars |
    //     tab[HCAP]*8 | tag[HCAP]*2 | firsts[MAXV]*8 | cnt[MAXV]*4 |
    //     lists[MAXV*LCAP]*4 | ftab[fhcap]*8   (~35 MB at N=2M, fhcap=2^21)
    size_t base_need = npad + npad + 16384 * 8 + 512
                + (size_t)HCAP * 8 + (size_t)HCAP * 2
                + (size_t)MAXV * 8 + (size_t)MAXV * 4 + (size_t)MAXV * LCAP * 4;
    u32 fhcap = 1u << 22;                        // prefer 32MB fallback table
    if (ws_size < base_need + ((size_t)8 << 22)) fhcap = 1u << 21;
    if (ws_size < base_need + ((size_t)8 << 21)) return;
    u32 fhmask = fhcap - 1u;

    char* w = (char*)d_ws;
    u8*  flags  = (u8*)w;   w += npad;
    u8*  prefix = (u8*)w;   w += npad;
    int* bsums  = (int*)w;  w += 16384 * 4;
    int* bpre   = (int*)w;  w += 16384 * 4;
    int* total  = (int*)w;  w += 128;
    int* dflag  = (int*)w;  w += 128;
    int* fastflag = (int*)w; w += 256;
    u64* tab    = (u64*)w;  w += (size_t)HCAP * 8;
    u16* tag    = (u16*)w;  w += (size_t)HCAP * 2;
    u64* firsts = (u64*)w;  w += (size_t)MAXV * 8;
    int* cnt    = (int*)w;  w += (size_t)MAXV * 4;
    int* lists  = (int*)w;  w += (size_t)MAXV * LCAP * 4;
    u64* ftab   = (u64*)w;

    k_init<<<2048, 256, 0, stream>>>(tab, tag, cnt, N, (const u16*)pts,
                                     dflag, total, fastflag);
    Voxelization_87136296501765_kernel<<<nbp, 256, 0, stream>>>(
        pts, Peff, dflag, tab, tag);
    k_scan1<<<nbp, 256, 0, stream>>>(pts, Peff, dflag, tab, flags, prefix,
                                     bsums);
    k_scan2p<<<1, 256, 0, stream>>>(bsums, nbp, bpre, total, fastflag, out);
    k_assign_lookup<<<nbp + nbs4, 256, 0, stream>>>(
        pts, N, Peff, dflag, fastflag, flags, prefix, bpre, tab, tag,
        nbp, nbs4, hasSuffix, firsts, cnt, lists, ftab, fhcap);
    if (hasSuffix) {
        k_finsert<<<2048, 256, 0, stream>>>(fastflag, hasSuffix, pts, N,
                                            dflag, ftab, fhmask, flags);
        k_fscan1<<<2048, 256, 0, stream>>>(fastflag, hasSuffix, flags,
                                           prefix, bsums, N);
        k_fscan2<<<1, 256, 0, stream>>>(fastflag, hasSuffix, bsums, nb, bpre,
                                        total, out);
        k_fassign<<<2048, 256, 0, stream>>>(fastflag, hasSuffix, pts, N,
                                            dflag, flags, prefix, bpre, ftab,
                                            fhmask, firsts, cnt, lists);
    }
    k_write<<<(MAXV + 255) / 256, 256, 0, stream>>>(pts, dflag, firsts, cnt,
                                                    lists, total, out);
}

// Round 15
// 156.300 us; speedup vs baseline: 1.2260x; 1.0195x over previous
//

#include <hip/hip_runtime.h>
#include <hip/hip_bf16.h>

// Deterministic hard_voxelize. Round 30: R29 skeleton (159.3us ~= 157.9 best,
// reproduced) + final parametric shave (the only change class that never
// regressed this session):
//  - PPREF 184320 -> 156672 (612 blocks): reachable cells for bench input =
//    1000x1000x40 = 40M; E[distinct(156672)] ~= 156.4K >= 150K with 6.4K
//    margin (sigma ~20, deterministic input). Adversarial inputs take the
//    gated fallback (correct, perf-irrelevant). Insert RMW / scan1 / prefix
//    assign -15%.
//  - Gated fallback grids 2048 -> 512 blocks (grid-stride, correct at any
//    grid; gated-off empty dispatches drain ~4x faster).
// Tested-and-rejected levers: coop launch (R21, breaks graph capture);
// dispatch-count cuts (R23, neutral); MLP x8 (R25, TLP-starved); NT loads
// (R25, breaks line reuse); scan||suffix overlap (R28, barrier-ladder is a
// bad co-residency partner for latency-bound gathers). Remaining wall =
// harness poison fills (~43us each, 78-80% HBM peak) + insert at scattered-
// RMW law + suffix at TLP-saturated latency floor (MLP x4) + write store
// floor + small dispatch gaps.
// Pipeline: init, insert, scan1, scan2p, assign+lookup(+gated finit),
// [4 gated fallback], write = 10 plain dispatches.

#define MAXV 150000
#define MAXP 10
#define LCAP 12
#define GXC 1504
#define GYC 1504
#define GZC 40

#define PPREF 156672           // prefix length (612 blocks); distinct >= MAXV
#define HC 19
#define HCAP (1u << HC)        // 524288 slots; load ~0.30 at P=156K
#define HMASK (HCAP - 1u)

#define OUT_COORS 7500000
#define OUT_NPV   7950000
#define OUT_VNUM  8100000
#define EMPTY64 0xFFFFFFFFFFFFFFFFULL

typedef unsigned char u8;
typedef unsigned short u16;
typedef unsigned int u32;
typedef unsigned long long u64;

// 16B vector load legal at 4B alignment on gfx950 (dword ops need 4B align).
typedef struct __attribute__((packed, aligned(4))) { float x, y, z, w; } f4u;

__device__ __forceinline__ u16 f2bf(float v) {  // round-to-nearest-even
    u32 b = __float_as_uint(v);
    return (u16)((b + 0x7FFFu + ((b >> 16) & 1u)) >> 16);
}
__device__ __forceinline__ float bf2f(u16 u) {
    return __uint_as_float(((u32)u) << 16);
}
__device__ __forceinline__ float bfround(float v) { return bf2f(f2bf(v)); }

__device__ __forceinline__ u32 hslot(int key) {
    return (((u32)key * 2654435761u) >> 12) & HMASK;
}
__device__ __forceinline__ u16 htag(int key) {  // independent 2nd hash, !=0
    return (u16)((((u32)key) * 0x85EBCA6Bu) >> 16) | (u16)1;
}
__device__ __forceinline__ u32 fhslot(int key, u32 fhmask) {
    return (((u32)key * 2654435761u) >> 9) & fhmask;
}

__device__ __forceinline__ float load_ch(const void* pts, int i, int j, int bf) {
    if (bf) return bf2f(((const u16*)pts)[i * 5 + j]);
    return ((const float*)pts)[i * 5 + j];
}

// Exact f32 sub+div+floor, matching reference arithmetic. -1 if out of range.
// f32 path: one dwordx4 covers x,y,z (row stride 20B >= 16B, no OOB).
__device__ __forceinline__ int point_key(const void* pts, int i, int bf) {
    float x, y, z;
    if (bf) {
        const u16* p = (const u16*)pts + (size_t)i * 5;
        x = bf2f(p[0]); y = bf2f(p[1]); z = bf2f(p[2]);
    } else {
        f4u v = *(const f4u*)((const float*)pts + (size_t)i * 5);
        x = v.x; y = v.y; z = v.z;
    }
    int cx = (int)floorf((x - (-75.2f)) / 0.1f);
    int cy = (int)floorf((y - (-75.2f)) / 0.1f);
    int cz = (int)floorf((z - (-2.0f)) / 0.15f);
    if (cx < 0 || cx >= GXC || cy < 0 || cy >= GYC || cz < 0 || cz >= GZC) return -1;
    return (cz * GYC + cy) * GXC + cx;
}

// Init (+ fused dtype detect in block 0): tab=EMPTY, tag=0, cnt=0, scalars.
__global__ void k_init(u64* tab, u16* tag, int* cnt, int N, const u16* raw,
                       int* dflag, int* total, int* fastflag) {
    if (blockIdx.x == 0) {
        __shared__ int v32;
        __shared__ int v16;
        if (threadIdx.x == 0) { v32 = 0; v16 = 0; }
        __syncthreads();
        int r = (int)threadIdx.x * 37;
        if (r >= N) r = N > 0 ? N - 1 : 0;
        const float* p32 = (const float*)raw;
        float a3 = p32[r * 5 + 3];
        float a4 = p32[r * 5 + 4];
        float b3 = bf2f(raw[r * 5 + 3]);
        float b4 = bf2f(raw[r * 5 + 4]);
        int ok32 = (a3 == a3) && (a4 == a4) &&
                   (a3 >= -0.001f) && (a3 <= 1.001f) && (a4 >= -0.001f) && (a4 <= 1.001f);
        int okbf = (b3 == b3) && (b4 == b4) &&
                   (b3 >= -0.001f) && (b3 <= 1.001f) && (b4 >= -0.001f) && (b4 <= 1.001f);
        if (ok32) atomicAdd(&v32, 1);
        if (okbf) atomicAdd(&v16, 1);
        __syncthreads();
        if (threadIdx.x == 0) *dflag = (v16 > v32) ? 1 : 0;
    }
    int stride = gridDim.x * blockDim.x;
    int i0 = blockIdx.x * blockDim.x + threadIdx.x;
    for (u32 i = (u32)i0; i < HCAP; i += (u32)stride) {
        tab[i] = EMPTY64;
        tag[i] = 0;
    }
    for (int i = i0; i < MAXV; i += stride) cnt[i] = 0;
    if (i0 == 0) { *total = 0; *fastflag = 0; }
}

// Canonical kernel: PURE packed u64 hash insert over the prefix.
// CAS-claim (winner writes tag); same-key -> atomicMin by point idx.
__global__ void Voxelization_87136296501765_kernel(
        const void* pts, int Peff, const int* dflag, u64* tab, u16* tag) {
    int i = blockIdx.x * 256 + threadIdx.x;
    if (i >= Peff) return;
    int key = point_key(pts, i, *dflag);
    if (key < 0) return;
    u64 mine = ((u64)(u32)key << 32) | (u32)i;
    u32 slot = hslot(key);
    for (;;) {                      // claims <= Peff <= HCAP/2: terminates
        u64 prev = atomicCAS(&tab[slot], EMPTY64, mine);
        if (prev == EMPTY64) { tag[slot] = htag(key); break; }
        if ((u32)(prev >> 32) == (u32)key) {
            if ((u32)prev > (u32)i) atomicMin(&tab[slot], mine);
            break;
        }
        slot = (slot + 1u) & HMASK;
    }
}

// Rank scan over the prefix. is-first recomputed by probing the quiescent
// table: isf = (min idx at key's slot == i).
__global__ void k_scan1(const void* pts, int Peff, const int* dflag,
                        const u64* tab, u8* flags, u8* prefix, int* bsums) {
    __shared__ int sh[256];
    int t = threadIdx.x;
    int i = blockIdx.x * 256 + t;
    int isf = 0;
    if (i < Peff) {
        int key = point_key(pts, i, *dflag);
        if (key >= 0) {
            u32 slot = hslot(key);
            for (;;) {
                u64 e = tab[slot];
                if ((u32)(e >> 32) == (u32)key) { isf = ((u32)e == (u32)i); break; }
                if (e == EMPTY64) break;   // unreachable (key inserted)
                slot = (slot + 1u) & HMASK;
            }
        }
        flags[i] = (u8)isf;
    }
    sh[t] = isf;
    __syncthreads();
    for (int off = 1; off < 256; off <<= 1) {
        int xv = (t >= off) ? sh[t - off] : 0;
        __syncthreads();
        sh[t] += xv;
        __syncthreads();
    }
    if (i < Peff) prefix[i] = (u8)(sh[t] - isf);
    if (t == 255) bsums[blockIdx.x] = sh[255];
}

// Single-block scan of nbp (<=612) chunk sums. Writes total, fastflag, vnum.
__global__ void k_scan2p(const int* bsums, int nbp, int* bpre,
                         int* total, int* fastflag, float* out) {
    __shared__ int sh[256];
    int t = threadIdx.x;
    int C = (nbp + 255) / 256;
    int lo = t * C;
    int hi = lo + C < nbp ? lo + C : nbp;
    int s = 0;
    for (int i = lo; i < hi; i++) s += bsums[i];
    sh[t] = s;
    __syncthreads();
    for (int off = 1; off < 256; off <<= 1) {
        int xv = (t >= off) ? sh[t - off] : 0;
        __syncthreads();
        sh[t] += xv;
        __syncthreads();
    }
    int run = sh[t] - s;
    for (int i = lo; i < hi; i++) { bpre[i] = run; run += bsums[i]; }
    if (t == 255) {
        int T = sh[255];
        *total = T;
        *fastflag = (T >= MAXV) ? 1 : 0;
        if (T > MAXV) T = MAXV;
        out[OUT_VNUM] = bfround((float)T);
    }
}

// Fused assign + suffix lookup (MLP x4) + gated fallback-init.
__global__ void k_assign_lookup(const void* pts, int N, int Peff,
                                const int* dflag, const int* fastflag,
                                u8* flags, const u8* prefix,
                                const int* bpre, const u64* tab,
                                const u16* tag, int nbp, int nbs4,
                                int hasSuffix,
                                u64* firsts, int* cnt, int* lists,
                                u64* ftab, u32 fhcap) {
    int b = blockIdx.x;
    int t = threadIdx.x;
    int fast = *fastflag;
    if (fast || !hasSuffix) {
        if (b < nbp) {
            int i = b * 256 + t;
            if (i < Peff) {
                int key = point_key(pts, i, *dflag);
                if (key >= 0) {
                    if (flags[i]) {
                        int v = (int)prefix[i] + bpre[b];
                        if (v < MAXV)
                            firsts[v] = ((u64)(u32)key << 32) | (u32)i;
                    } else {
                        u32 slot = hslot(key);        // dup: find first idx
                        for (;;) {
                            u64 e = tab[slot];
                            if ((u32)(e >> 32) == (u32)key) {
                                u32 f = (u32)e;
                                int v = (int)prefix[f] + bpre[f >> 8];
                                if (v < MAXV) {
                                    int pos = atomicAdd(&cnt[v], 1);
                                    if (pos < LCAP) lists[v * LCAP + pos] = i;
                                }
                                break;
                            }
                            if (e == EMPTY64) break;  // unreachable
                            slot = (slot + 1u) & HMASK;
                        }
                    }
                }
            }
        } else if (b < nbp + nbs4 && fast) {
            int bf = *dflag;
            int base = Peff + (b - nbp) * 1024 + t;
            int idx[4];
            int key[4];
#pragma unroll
            for (int s = 0; s < 4; s++) {        // 4 independent pts chains
                int i = base + s * 256;
                idx[s] = i;
                key[s] = (i < N) ? point_key(pts, i, bf) : -1;
            }
            u32 slot[4];
            u16 tg[4];
            u16 g[4];
#pragma unroll
            for (int s = 0; s < 4; s++) {        // 4 independent tag loads
                if (key[s] >= 0) {
                    slot[s] = hslot(key[s]);
                    tg[s] = htag(key[s]);
                    g[s] = tag[slot[s]];
                }
            }
#pragma unroll
            for (int s = 0; s < 4; s++) {        // resolve (tag-hit ~0.65%)
                if (key[s] < 0) continue;
                u32 sl = slot[s];
                u16 gg = g[s];
                for (;;) {
                    if (gg == 0) break;          // voxel not opened -> dropped
                    if (gg == tg[s]) {
                        u64 e = tab[sl];
                        if ((u32)(e >> 32) == (u32)key[s]) {
                            u32 f = (u32)e;
                            int v = (int)prefix[f] + bpre[f >> 8];
                            if (v < MAXV) {
                                int pos = atomicAdd(&cnt[v], 1);
                                if (pos < LCAP) lists[v * LCAP + pos] = idx[s];
                            }
                            break;
                        }                        // false positive -> continue
                    }
                    sl = (sl + 1u) & HMASK;
                    gg = tag[sl];
                }
            }
        }
    } else {
        // gated fallback init (distinct(prefix) < MAXV, suffix exists)
        int tid = b * 256 + t;
        int gsz = gridDim.x * 256;
        for (u32 i = (u32)tid; i < fhcap; i += (u32)gsz) ftab[i] = EMPTY64;
        for (int i = tid; i < MAXV; i += gsz) cnt[i] = 0;
        int bf = *dflag;
        for (int i = tid; i < N; i += gsz)
            flags[i] = (u8)(point_key(pts, i, bf) >= 0);
    }
}

// ---- Gated fallback (distinct(prefix) < MAXV; never on bench input) ----

__global__ void k_finsert(const int* fastflag, int hasSuffix, const void* pts,
                          int N, const int* dflag, u64* ftab, u32 fhmask,
                          u8* flags) {
    if (*fastflag || !hasSuffix) return;
    int stride = gridDim.x * blockDim.x;
    int bf = *dflag;
    for (int i = blockIdx.x * blockDim.x + threadIdx.x; i < N; i += stride) {
        int key = point_key(pts, i, bf);
        if (key < 0) continue;
        u64 mine = ((u64)(u32)key << 32) | (u32)i;
        u32 slot = fhslot(key, fhmask);
        for (u32 tries = 0; tries <= fhmask; ++tries) {  // bounded
            u64 prev = atomicCAS(&ftab[slot], EMPTY64, mine);
            if (prev == EMPTY64) break;
            if ((u32)(prev >> 32) == (u32)key) {
                u32 pm = (u32)prev;
                u32 eidx;
                if (pm > (u32)i) {
                    u64 old = atomicMin(&ftab[slot], mine);
                    u32 om = (u32)old;
                    eidx = (om > (u32)i) ? om : (u32)i;
                } else {
                    eidx = (u32)i;
                }
                flags[eidx] = 0;   // flags written in prior dispatch: safe
                break;
            }
            slot = (slot + 1u) & fhmask;
        }
    }
}

__global__ void k_fscan1(const int* fastflag, int hasSuffix, const u8* flags,
                         u8* prefix, int* bsums, int n) {
    if (*fastflag || !hasSuffix) return;
    __shared__ int sh[256];
    int t = threadIdx.x;
    int nb = (n + 255) >> 8;
    for (int chunk = blockIdx.x; chunk < nb; chunk += gridDim.x) {
        int i = chunk * 256 + t;
        int v = (i < n) ? (int)flags[i] : 0;
        sh[t] = v;
        __syncthreads();
        for (int off = 1; off < 256; off <<= 1) {
            int xv = (t >= off) ? sh[t - off] : 0;
            __syncthreads();
            sh[t] += xv;
            __syncthreads();
        }
        if (i < n) prefix[i] = (u8)(sh[t] - v);
        if (t == 255) bsums[chunk] = sh[255];
        __syncthreads();
    }
}

__global__ void k_fscan2(const int* fastflag, int hasSuffix, const int* bsums,
                         int nb, int* bpre, int* total, float* out) {
    if (*fastflag || !hasSuffix) return;
    __shared__ int sh[256];
    int t = threadIdx.x;
    int C = (nb + 255) / 256;
    int lo = t * C;
    int hi = lo + C < nb ? lo + C : nb;
    int s = 0;
    for (int i = lo; i < hi; i++) s += bsums[i];
    sh[t] = s;
    __syncthreads();
    for (int off = 1; off < 256; off <<= 1) {
        int xv = (t >= off) ? sh[t - off] : 0;
        __syncthreads();
        sh[t] += xv;
        __syncthreads();
    }
    int run = sh[t] - s;
    for (int i = lo; i < hi; i++) { bpre[i] = run; run += bsums[i]; }
    if (t == 255) {
        int T = sh[255];
        *total = T;
        if (T > MAXV) T = MAXV;
        out[OUT_VNUM] = bfround((float)T);
    }
}

__global__ void k_fassign(const int* fastflag, int hasSuffix, const void* pts,
                          int N, const int* dflag, const u8* flags,
                          const u8* prefix, const int* bpre, const u64* ftab,
                          u32 fhmask, u64* firsts, int* cnt, int* lists) {
    if (*fastflag || !hasSuffix) return;
    int stride = gridDim.x * blockDim.x;
    int bf = *dflag;
    for (int i = blockIdx.x * blockDim.x + threadIdx.x; i < N; i += stride) {
        int key = point_key(pts, i, bf);
        if (key < 0) continue;
        if (flags[i]) {
            int v = (int)prefix[i] + bpre[i >> 8];
            if (v < MAXV)
                firsts[v] = ((u64)(u32)key << 32) | (u32)i;
        } else {
            u32 slot = fhslot(key, fhmask);
            for (u32 tries = 0; tries <= fhmask; ++tries) {
                u64 e = ftab[slot];
                if (e == EMPTY64) break;
                if ((u32)(e >> 32) == (u32)key) {
                    u32 f = (u32)e;
                    int v = (int)prefix[f] + bpre[f >> 8];
                    if (v < MAXV) {
                        int pos = atomicAdd(&cnt[v], 1);
                        if (pos < LCAP) lists[v * LCAP + pos] = i;
                    }
                    break;
                }
                slot = (slot + 1u) & fhmask;
            }
        }
    }
}

// Data row copy: f32 path reads ch0..3 via one dwordx4 + ch4 scalar.
__device__ __forceinline__ void write_row(const void* pts, int p, int bf,
                                          float* dst) {
    if (bf) {
        const u16* q = (const u16*)pts + (size_t)p * 5;
#pragma unroll
        for (int j = 0; j < 5; j++) dst[j] = bfround(bf2f(q[j]));
    } else {
        const float* base = (const float*)pts + (size_t)p * 5;
        f4u v = *(const f4u*)base;
        dst[0] = bfround(v.x);
        dst[1] = bfround(v.y);
        dst[2] = bfround(v.z);
        dst[3] = bfround(v.w);
        dst[4] = bfround(base[4]);
    }
}

// Sole output writer (d_out is poisoned each call): per v zero-fills the
// 200B row via 25 float2 stores, then overwrites the ~1.05 data rows;
// coors (coalesced in v), npv.
__global__ void k_write(const void* pts, const int* dflag, const u64* firsts,
                        const int* cnt, const int* lists, const int* total,
                        float* out) {
    int v = blockIdx.x * blockDim.x + threadIdx.x;
    if (v >= MAXV) return;
    int T = *total;
    if (T > MAXV) T = MAXV;
    float* dst = out + (size_t)v * MAXP * 5;
    float2* d2 = (float2*)dst;          // v*200B -> 8B aligned
#pragma unroll
    for (int j = 0; j < 25; j++) d2[j] = make_float2(0.0f, 0.0f);
    if (v >= T) {
        out[OUT_COORS + v * 3 + 0] = -1.0f;
        out[OUT_COORS + v * 3 + 1] = -1.0f;
        out[OUT_COORS + v * 3 + 2] = -1.0f;
        out[OUT_NPV + v] = 0.0f;
        return;
    }
    u64 fe = firsts[v];
    u32 key = (u32)(fe >> 32);
    int f = (int)(u32)fe;
    int cx = (int)(key % GXC);
    u32 r = key / GXC;
    int cy = (int)(r % GYC);
    int cz = (int)(r / GYC);
    out[OUT_COORS + v * 3 + 0] = bfround((float)cz);
    out[OUT_COORS + v * 3 + 1] = bfround((float)cy);
    out[OUT_COORS + v * 3 + 2] = bfround((float)cx);
    int c = cnt[v];
    int np = 1 + c;
    if (np > MAXP) np = MAXP;
    out[OUT_NPV + v] = (float)np;
    int bf = *dflag;
    write_row(pts, f, bf, dst);
    if (c > 0) {
        int m = (c < LCAP) ? c : LCAP;
        int idx[LCAP];
        for (int j = 0; j < m; j++) idx[j] = lists[v * LCAP + j];
        for (int a = 1; a < m; a++) {  // sort dup indices -> insertion order
            int kk = idx[a];
            int b2 = a - 1;
            while (b2 >= 0 && idx[b2] > kk) { idx[b2 + 1] = idx[b2]; b2--; }
            idx[b2 + 1] = kk;
        }
        for (int rr = 1; rr < np; rr++)
            write_row(pts, idx[rr - 1], bf, dst + rr * 5);
    }
}

extern "C" void kernel_launch(void* const* d_in, const int* in_sizes, int n_in,
                              void* d_out, int out_size, void* d_ws, size_t ws_size,
                              hipStream_t stream) {
    (void)n_in; (void)out_size;
    const void* pts = d_in[0];
    int N = in_sizes[0] / 5;
    float* out = (float*)d_out;
    if (N <= 0 || N > 16384 * 256) return;

    int Peff = N < PPREF ? N : PPREF;
    int nbp = (Peff + 255) / 256;
    int nbs4 = (N > Peff) ? (N - Peff + 1023) / 1024 : 0;
    int nb = (N + 255) / 256;
    int hasSuffix = (N > Peff) ? 1 : 0;
    size_t npad = ((size_t)N + 255) & ~(size_t)255;

    // ws: flags[npad] | prefix[npad] | bsums/bpre[16384]*4 | scalars |
    //     tab[HCAP]*8 | tag[HCAP]*2 | firsts[MAXV]*8 | cnt[MAXV]*4 |
    //     lists[MAXV*LCAP]*4 | ftab[fhcap]*8   (~35 MB at N=2M, fhcap=2^21)
    size_t base_need = npad + npad + 16384 * 8 + 512
                + (size_t)HCAP * 8 + (size_t)HCAP * 2
                + (size_t)MAXV * 8 + (size_t)MAXV * 4 + (size_t)MAXV * LCAP * 4;
    u32 fhcap = 1u << 22;                        // prefer 32MB fallback table
    if (ws_size < base_need + ((size_t)8 << 22)) fhcap = 1u << 21;
    if (ws_size < base_need + ((size_t)8 << 21)) return;
    u32 fhmask = fhcap - 1u;

    char* w = (char*)d_ws;
    u8*  flags  = (u8*)w;   w += npad;
    u8*  prefix = (u8*)w;   w += npad;
    int* bsums  = (int*)w;  w += 16384 * 4;
    int* bpre   = (int*)w;  w += 16384 * 4;
    int* total  = (int*)w;  w += 128;
    int* dflag  = (int*)w;  w += 128;
    int* fastflag = (int*)w; w += 256;
    u64* tab    = (u64*)w;  w += (size_t)HCAP * 8;
    u16* tag    = (u16*)w;  w += (size_t)HCAP * 2;
    u64* firsts = (u64*)w;  w += (size_t)MAXV * 8;
    int* cnt    = (int*)w;  w += (size_t)MAXV * 4;
    int* lists  = (int*)w;  w += (size_t)MAXV * LCAP * 4;
    u64* ftab   = (u64*)w;

    k_init<<<2048, 256, 0, stream>>>(tab, tag, cnt, N, (const u16*)pts,
                                     dflag, total, fastflag);
    Voxelization_87136296501765_kernel<<<nbp, 256, 0, stream>>>(
        pts, Peff, dflag, tab, tag);
    k_scan1<<<nbp, 256, 0, stream>>>(pts, Peff, dflag, tab, flags, prefix,
                                     bsums);
    k_scan2p<<<1, 256, 0, stream>>>(bsums, nbp, bpre, total, fastflag, out);
    k_assign_lookup<<<nbp + nbs4, 256, 0, stream>>>(
        pts, N, Peff, dflag, fastflag, flags, prefix, bpre, tab, tag,
        nbp, nbs4, hasSuffix, firsts, cnt, lists, ftab, fhcap);
    if (hasSuffix) {
        k_finsert<<<512, 256, 0, stream>>>(fastflag, hasSuffix, pts, N,
                                           dflag, ftab, fhmask, flags);
        k_fscan1<<<512, 256, 0, stream>>>(fastflag, hasSuffix, flags,
                                          prefix, bsums, N);
        k_fscan2<<<1, 256, 0, stream>>>(fastflag, hasSuffix, bsums, nb, bpre,
                                        total, out);
        k_fassign<<<512, 256, 0, stream>>>(fastflag, hasSuffix, pts, N,
                                           dflag, flags, prefix, bpre, ftab,
                                           fhmask, firsts, cnt, lists);
    }
    k_write<<<(MAXV + 255) / 256, 256, 0, stream>>>(pts, dflag, firsts, cnt,
                                                    lists, total, out);
}